// Round 5
// baseline (4235.376 us; speedup 1.0000x reference)
//
#include <hip/hip_runtime.h>
#include <hip/hip_cooperative_groups.h>

namespace cg = cooperative_groups;

#define NPT 20000
#define DIMK 256
#define HD 128
#define KC 64
#define NT 17
#define NSLOT (KC*NT)          // 1088
#define SINK_IT 50
#define G_MAIN 144
#define BT 512
#define WAVES_MAIN (G_MAIN*(BT/64))   // 1152
#define CH_LL ((NPT + G_MAIN - 1)/G_MAIN)  // 139
#define UPT 40                 // points per thread in kmeans++ (512*40 >= 20000)

// ---- scratch offsets (floats) inside the T region of d_out ----
#define OFF_H     0
#define OFF_CL    (NPT*HD)                   // 2,560,000
#define OFF_Q     (OFF_CL + NPT*KC)          // 3,840,000
#define OFF_LS    (OFF_Q + 64*NPT)           // 5,120,000
#define OFF_LOGU  (OFF_LS + NPT*KC)          // 6,400,000
#define OFF_ORDER (OFF_LOGU + NPT)
#define OFF_TSV   (OFF_ORDER + NPT)
#define OFF_OFFS  (OFF_TSV + NPT)
#define OFF_CENTS (OFF_OFFS + 64)
#define OFF_I0    (OFF_CENTS + 128)
#define OFF_SUB   (OFF_I0 + 32)
#define OFF_PMAXP (OFF_SUB + 128)
#define OFF_PSUMP (OFF_PMAXP + NT*8*KC)
#define OFF_LASTP (OFF_PSUMP + NT*8*KC)
#define OFF_LLOYD (OFF_LASTP + 32)
// end ~= 6.55M floats << 21.76M floats of T region

__device__ __forceinline__ void tf2x32(unsigned k0, unsigned k1,
                                       unsigned x0, unsigned x1,
                                       unsigned& o0, unsigned& o1) {
  // JAX threefry2x32 block cipher (20 rounds, Random123 constants)
  unsigned ks0 = k0, ks1 = k1, ks2 = k0 ^ k1 ^ 0x1BD11BDAu;
  x0 += ks0; x1 += ks1;
  const int rot[2][4] = {{13,15,26,6},{17,29,16,24}};
  unsigned ks[3] = {ks0, ks1, ks2};
  #pragma unroll
  for (int i = 0; i < 5; ++i) {
    #pragma unroll
    for (int r = 0; r < 4; ++r) {
      int rr = rot[i & 1][r];
      x0 += x1;
      x1 = (x1 << rr) | (x1 >> (32 - rr));
      x1 ^= x0;
    }
    x0 += ks[(i+1)%3];
    x1 += ks[(i+2)%3] + (unsigned)(i+1);
  }
  o0 = x0; o1 = x1;
}

// ---------------- K1: key chain (partitionable) + randint i0 (with INTERNAL SPLIT) ----
// split(key): child i = cipher(key, counter=(0,i)), both output words
// randint(k0,(),0,20000) int32:
//   k1,k2 = split(k0)
//   higher = fold(cipher(k1,(0,0))); lower = fold(cipher(k2,(0,0)))   [fold = o0^o1]
//   mult = (2^16 % span)^2 % span = 7296
//   i0 = ((higher%span)*mult + lower%span) % span   (uint32 arithmetic)
__global__ void k_keys(unsigned* sub, int* i0p) {
  if (threadIdx.x != 0 || blockIdx.x != 0) return;
  unsigned key0 = 0u, key1 = 42u;            // jax.random.key(42)
  unsigned c0, c1, s0, s1;
  // key, k0 = split(key)
  tf2x32(key0, key1, 0u, 0u, c0, c1);
  tf2x32(key0, key1, 0u, 1u, s0, s1);
  key0 = c0; key1 = c1;
  // randint's internal split of k0:
  unsigned k1a, k1b, k2a, k2b;
  tf2x32(s0, s1, 0u, 0u, k1a, k1b);
  tf2x32(s0, s1, 0u, 1u, k2a, k2b);
  unsigned h0, h1, l0, l1;
  tf2x32(k1a, k1b, 0u, 0u, h0, h1);
  tf2x32(k2a, k2b, 0u, 0u, l0, l1);
  unsigned hb = h0 ^ h1, lb = l0 ^ l1;       // partitionable 32-bit fold
  unsigned span = 20000u;
  unsigned m1 = 65536u % span;               // 5536
  unsigned mult = (unsigned)(((unsigned long long)m1 * m1) % span);  // 7296
  unsigned off32 = (hb % span) * mult + (lb % span);   // uint32, no overflow
  *i0p = (int)(off32 % span);
  sub[0] = 0u; sub[1] = 0u;
  for (int i = 1; i < KC; ++i) {
    tf2x32(key0, key1, 0u, 0u, c0, c1);
    tf2x32(key0, key1, 0u, 1u, s0, s1);
    key0 = c0; key1 = c1;
    sub[2*i] = s0; sub[2*i+1] = s1;
  }
}

// ---------------- K2: gumbel noise g[step][i] = -log(-log(u)), partitionable 32-bit ----
__global__ __launch_bounds__(256) void k_gumbel(const unsigned* __restrict__ sub,
                                                float* __restrict__ Q) {
  int s = blockIdx.y + 1;
  int i = blockIdx.x * 256 + threadIdx.x;
  if (i >= NPT) return;
  unsigned o0, o1;
  tf2x32(sub[2*s], sub[2*s+1], 0u, (unsigned)i, o0, o1);
  unsigned bits = o0 ^ o1;                    // partitionable 32-bit fold
  unsigned fb = (bits >> 9) | 0x3f800000u;
  float u = __uint_as_float(fb) - 1.0f;
  if (u == 0.0f) u = 1.17549435e-38f;         // minval = finfo.tiny
  Q[(size_t)s*NPT + i] = -logf(-logf(u));     // true gumbel, mirrors reference
}

// ---------------- K3: h = selu(emb @ W1 + b1) ----------------
__global__ __launch_bounds__(256) void k_gemm(const float* __restrict__ emb,
                                              const float* __restrict__ W1,
                                              const float* __restrict__ b1,
                                              float* __restrict__ h) {
  __shared__ float As[64][64];   // [k][row]
  __shared__ float Bs[64][HD];   // [k][col]
  const int m0 = blockIdx.x * 64;
  const int tid = threadIdx.x;
  const int tx = tid & 31;        // col group (4 cols)
  const int ty = tid >> 5;        // row group (8 rows)
  float acc[8][4];
  #pragma unroll
  for (int a = 0; a < 8; ++a)
    #pragma unroll
    for (int c = 0; c < 4; ++c) acc[a][c] = 0.f;

  for (int kc = 0; kc < DIMK; kc += 64) {
    #pragma unroll
    for (int it = 0; it < 4; ++it) {
      int f = it*256 + tid;
      int r = f >> 4;
      int kk = (f & 15) << 2;
      float4 v = make_float4(0.f,0.f,0.f,0.f);
      if (m0 + r < NPT)
        v = *(const float4*)(emb + (size_t)(m0 + r)*DIMK + kc + kk);
      As[kk+0][r] = v.x; As[kk+1][r] = v.y; As[kk+2][r] = v.z; As[kk+3][r] = v.w;
    }
    #pragma unroll
    for (int it = 0; it < 8; ++it) {
      int f = it*256 + tid;
      int kk = f >> 5;
      int cc = (f & 31) << 2;
      *(float4*)&Bs[kk][cc] = *(const float4*)(W1 + (size_t)(kc + kk)*HD + cc);
    }
    __syncthreads();
    #pragma unroll 8
    for (int kk = 0; kk < 64; ++kk) {
      float4 a0 = *(float4*)&As[kk][ty*8];
      float4 a1 = *(float4*)&As[kk][ty*8+4];
      float4 bb = *(float4*)&Bs[kk][tx*4];
      float av[8] = {a0.x,a0.y,a0.z,a0.w,a1.x,a1.y,a1.z,a1.w};
      float bv[4] = {bb.x,bb.y,bb.z,bb.w};
      #pragma unroll
      for (int a = 0; a < 8; ++a)
        #pragma unroll
        for (int c = 0; c < 4; ++c) acc[a][c] += av[a]*bv[c];
    }
    __syncthreads();
  }
  const float SC = 1.0507009873554805f, AL = 1.6732632423543772f;
  #pragma unroll
  for (int a = 0; a < 8; ++a) {
    int r = m0 + ty*8 + a;
    if (r >= NPT) continue;
    float4 o;
    float* po = &o.x;
    #pragma unroll
    for (int c = 0; c < 4; ++c) {
      float x = acc[a][c] + b1[tx*4 + c];
      float v = (x > 0.f) ? x : AL * expm1f(x);
      po[c] = SC * v;
    }
    *(float4*)(h + (size_t)r*HD + tx*4) = o;
  }
}

// ---------------- K4: c_learned = sqdist(h, protos[:64]) ----------------
__global__ __launch_bounds__(256) void k_cl(const float* __restrict__ h,
                                            const float* __restrict__ protos,
                                            float* __restrict__ cl) {
  __shared__ float ps[KC][129];
  __shared__ float hs[4][HD];
  const int tid = threadIdx.x;
  #pragma unroll
  for (int it = 0; it < 32; ++it) {
    int f = it*256 + tid;
    ps[f >> 7][f & 127] = protos[f];
  }
  const int i0r = blockIdx.x * 4;
  for (int f = tid; f < 4*HD; f += 256) {
    int rr = f >> 7, d = f & 127;
    int gi = i0r + rr;
    hs[rr][d] = (gi < NPT) ? h[(size_t)gi*HD + d] : 0.f;
  }
  __syncthreads();
  const int j = tid & 63, rq = tid >> 6;
  const int gi = i0r + rq;
  if (gi < NPT) {
    float dot = 0.f, hh = 0.f, pp = 0.f;
    #pragma unroll 8
    for (int d = 0; d < HD; ++d) {
      float a = hs[rq][d], b = ps[j][d];
      dot += a*b; hh += a*a; pp += b*b;
    }
    float c = hh + pp - 2.f*dot;
    cl[(size_t)gi*KC + j] = fmaxf(c, 0.f);
  }
}

// ---------------- K5: cooperative mega-kernel ----------------
union SMu {
  struct { unsigned cnt[BT][NT]; int tot[NT]; int base[NT]; } srt;
  struct { float cents[KC][2]; float red[8]; int redi[8]; float S; int bsel; } km;
  struct { float cents[KC][2]; int asg[CH_LL]; float comb[192]; } ll;
  struct { float cents[KC][2]; } cb;
  struct { float lv[NT][KC]; float gred[8][KC]; float lvl; float tmp[2]; } sk;
};

__global__ __launch_bounds__(BT, 2) void k_main(const float* pos, const int* jt,
                                                float* TS, float* vals) {
  __shared__ SMu sm;
  cg::grid_group grid = cg::this_grid();
  const int tid = threadIdx.x;
  const int b = blockIdx.x;
  const int lane = tid & 63;
  const int wv = tid >> 6;

  float* cl    = TS + OFF_CL;
  float* Q     = TS + OFF_Q;
  float* Ls    = TS + OFF_LS;
  float* logu  = TS + OFF_LOGU;
  int*   order = (int*)(TS + OFF_ORDER);
  int*   tsv   = (int*)(TS + OFF_TSV);
  int*   offs  = (int*)(TS + OFF_OFFS);
  float* centsg= TS + OFF_CENTS;
  int*   i0p   = (int*)(TS + OFF_I0);
  float* pmaxp = TS + OFF_PMAXP;
  float* psump = TS + OFF_PSUMP;
  float* lastp = TS + OFF_LASTP;
  float* llp   = TS + OFF_LLOYD;

  // ===== phase S: stable counting sort of rows by joint type (block 0) =====
  if (b == 0) {
    const int CHS = (NPT + BT - 1)/BT;       // 40
    const int r0 = tid*CHS, r1 = min(NPT, r0 + CHS);
    for (int t = 0; t < NT; ++t) sm.srt.cnt[tid][t] = 0;
    __syncthreads();
    for (int r = r0; r < r1; ++r) sm.srt.cnt[tid][jt[r]]++;
    __syncthreads();
    if (tid < NT) {
      unsigned s = 0;
      for (int i = 0; i < BT; ++i) s += sm.srt.cnt[i][tid];
      sm.srt.tot[tid] = (int)s;
    }
    __syncthreads();
    if (tid == 0) {
      int acc = 0;
      for (int t = 0; t < NT; ++t) { sm.srt.base[t] = acc; offs[t] = acc; acc += sm.srt.tot[t]; }
      offs[NT] = acc;
    }
    __syncthreads();
    if (tid < NT) {
      unsigned run = (unsigned)sm.srt.base[tid];
      for (int i = 0; i < BT; ++i) { unsigned c = sm.srt.cnt[i][tid]; sm.srt.cnt[i][tid] = run; run += c; }
    }
    __syncthreads();
    for (int r = r0; r < r1; ++r) {
      int t = jt[r];
      unsigned p = sm.srt.cnt[tid][t]++;
      order[p] = r; tsv[p] = t;
    }
  }
  grid.sync();

  // ===== phase KM: kmeans++ (block 0; points resident in registers) =====
  if (b == 0) {
    float px[UPT], py[UPT], dm[UPT];
    const int i0 = *i0p;
    const float c0x = pos[2*i0], c0y = pos[2*i0+1];
    if (tid == 0) { sm.km.cents[0][0] = c0x; sm.km.cents[0][1] = c0y; }
    #pragma unroll
    for (int u = 0; u < UPT; ++u) {
      int i = tid + u*BT;
      bool v = i < NPT;
      float x = v ? pos[2*i]   : 0.f;
      float y = v ? pos[2*i+1] : 0.f;
      px[u] = x; py[u] = y;
      float d = (x*x + y*y) + (c0x*c0x + c0y*c0y) - 2.f*(x*c0x + y*c0y);
      dm[u] = v ? fmaxf(d, 0.f) : 0.f;
    }
    __syncthreads();
    for (int s = 1; s < KC; ++s) {
      float loc = 0.f;
      #pragma unroll
      for (int u = 0; u < UPT; ++u) loc += dm[u];
      for (int o = 32; o; o >>= 1) loc += __shfl_xor(loc, o, 64);
      if (lane == 0) sm.km.red[wv] = loc;
      __syncthreads();
      if (tid == 0) {
        float S = 0.f;
        for (int w = 0; w < 8; ++w) S += sm.km.red[w];
        sm.km.S = S;
      }
      __syncthreads();
      const float invS = 1.0f/(sm.km.S + 1e-8f);
      float bsc = -3.4e38f; int bi = 0x7FFFFFFF;
      const float* Qs = Q + (size_t)s*NPT;
      #pragma unroll
      for (int u = 0; u < UPT; ++u) {
        int i = tid + u*BT;
        if (i < NPT) {
          // mirrors reference: argmax( log(probs + 1e-12) + gumbel )
          float sc = logf(dm[u]*invS + 1e-12f) + Qs[i];
          if (sc > bsc || (sc == bsc && i < bi)) { bsc = sc; bi = i; }
        }
      }
      for (int o = 32; o; o >>= 1) {
        float osc = __shfl_xor(bsc, o, 64);
        int   oid = __shfl_xor(bi, o, 64);
        if (osc > bsc || (osc == bsc && oid < bi)) { bsc = osc; bi = oid; }
      }
      __syncthreads();
      if (lane == 0) { sm.km.red[wv] = bsc; sm.km.redi[wv] = bi; }
      __syncthreads();
      if (tid == 0) {
        float bb = -3.4e38f; int bj = 0x7FFFFFFF;
        for (int w = 0; w < 8; ++w) {
          float v2 = sm.km.red[w]; int id2 = sm.km.redi[w];
          if (v2 > bb || (v2 == bb && id2 < bj)) { bb = v2; bj = id2; }
        }
        sm.km.bsel = bj;
      }
      __syncthreads();
      const int sel = sm.km.bsel;
      const float cx = pos[2*sel], cy = pos[2*sel+1];
      if (tid == 0) { sm.km.cents[s][0] = cx; sm.km.cents[s][1] = cy; }
      #pragma unroll
      for (int u = 0; u < UPT; ++u) {
        float x = px[u], y = py[u];
        float d = (x*x + y*y) + (cx*cx + cy*cy) - 2.f*(x*cx + y*cy);
        dm[u] = fminf(dm[u], fmaxf(d, 0.f));
      }
      __syncthreads();
    }
    if (tid < KC) { centsg[2*tid] = sm.km.cents[tid][0]; centsg[2*tid+1] = sm.km.cents[tid][1]; }
  }
  grid.sync();

  // ===== phase LL: 10 Lloyd iterations (all blocks, deterministic) =====
  const int ll_start = b * CH_LL;
  const int ll_cnt = max(0, min(NPT - ll_start, CH_LL));
  for (int it = 0; it < 10; ++it) {
    if (tid < KC) { sm.ll.cents[tid][0] = centsg[2*tid]; sm.ll.cents[tid][1] = centsg[2*tid+1]; }
    __syncthreads();
    if (tid < ll_cnt) {
      int i = ll_start + tid;
      float x = pos[2*i], y = pos[2*i+1];
      float bd = 3.4e38f; int bj = 0;
      #pragma unroll 4
      for (int j = 0; j < KC; ++j) {
        float cx = sm.ll.cents[j][0], cy = sm.ll.cents[j][1];
        float d = (x*x + y*y) + (cx*cx + cy*cy) - 2.f*(x*cx + y*cy);
        d = fmaxf(d, 0.f);
        if (d < bd) { bd = d; bj = j; }
      }
      sm.ll.asg[tid] = bj;
    }
    __syncthreads();
    if (wv == 0) {
      float sx = 0.f, sy = 0.f, cn = 0.f;
      for (int r = 0; r < ll_cnt; ++r) {
        int a = sm.ll.asg[r];
        int i = ll_start + r;
        float x = pos[2*i], y = pos[2*i+1];
        if (lane == a) { sx += x; sy += y; cn += 1.f; }
      }
      llp[((size_t)b*KC + lane)*3 + 0] = sx;
      llp[((size_t)b*KC + lane)*3 + 1] = sy;
      llp[((size_t)b*KC + lane)*3 + 2] = cn;
    }
    grid.sync();
    if (b == 0) {
      if (tid < 192) {
        int c = tid/3, f = tid - 3*(tid/3);
        float s = 0.f;
        for (int bb2 = 0; bb2 < G_MAIN; ++bb2) s += llp[((size_t)bb2*KC + c)*3 + f];
        sm.ll.comb[tid] = s;
      }
      __syncthreads();
      if (tid < KC) {
        float cn = sm.ll.comb[3*tid+2];
        if (cn > 0.f) {
          float dv = fmaxf(cn, 1.f);
          centsg[2*tid]   = sm.ll.comb[3*tid]   / dv;
          centsg[2*tid+1] = sm.ll.comb[3*tid+1] / dv;
        }
      }
    }
    grid.sync();
  }

  // ===== phase CB: Ls[ii][j] = -(c_spatial + 0.5*c_learned)/TAU, type-sorted =====
  if (tid < KC) { sm.cb.cents[tid][0] = centsg[2*tid]; sm.cb.cents[tid][1] = centsg[2*tid+1]; }
  __syncthreads();
  const int wid = b*(BT/64) + wv;
  for (int ii = wid; ii < NPT; ii += WAVES_MAIN) {
    int i = order[ii];
    float x = pos[2*i], y = pos[2*i+1];
    float cx = sm.cb.cents[lane][0], cy = sm.cb.cents[lane][1];
    float cs = (x*x + y*y) + (cx*cx + cy*cy) - 2.f*(x*cx + y*cy);
    cs = fmaxf(cs, 0.f);
    float cle = cl[(size_t)i*KC + lane];
    Ls[(size_t)ii*KC + lane] = -(cs + 0.5f*cle) / 0.05f;
  }
  grid.sync();

  // ===== phase SK: 50 Sinkhorn iterations =====
  for (int it = 0; it < SINK_IT; ++it) {
    // build log_v (lv) in LDS
    if (it == 0) {
      for (int s2 = tid; s2 < NT*KC; s2 += BT) ((float*)sm.sk.lv)[s2] = 0.f;
      if (tid == 0) sm.sk.lvl = 0.f;
    } else {
      for (int s2 = tid; s2 <= NT*KC; s2 += BT) {
        if (s2 < NT*KC) {
          int t = s2 >> 6, j = s2 & 63;
          float m = -3.4e38f;
          #pragma unroll
          for (int c = 0; c < 8; ++c) m = fmaxf(m, pmaxp[((t<<3)+c)*KC + j]);
          float a = 0.f;
          #pragma unroll
          for (int c = 0; c < 8; ++c) a += psump[((t<<3)+c)*KC + j] * __expf(pmaxp[((t<<3)+c)*KC + j] - m);
          ((float*)sm.sk.lv)[s2] = -(__logf(a) + m);
        } else {
          float m = -3.4e38f;
          #pragma unroll
          for (int c = 0; c < 8; ++c) m = fmaxf(m, lastp[c]);
          float a = 0.f;
          #pragma unroll
          for (int c = 0; c < 8; ++c) a += lastp[8+c] * __expf(lastp[c] - m);
          sm.sk.lvl = logf(18912.0f) - (__logf(a) + m);
        }
      }
    }
    __syncthreads();
    // row pass: log_u
    const float lvl = sm.sk.lvl;
    for (int ii = wid; ii < NPT; ii += WAVES_MAIN) {
      int t = tsv[ii];
      float x = Ls[(size_t)ii*KC + lane] + sm.sk.lv[t][lane];
      float m = x;
      for (int o = 32; o; o >>= 1) m = fmaxf(m, __shfl_xor(m, o, 64));
      m = fmaxf(m, lvl);
      float e = __expf(x - m);
      for (int o = 32; o; o >>= 1) e += __shfl_xor(e, o, 64);
      e += __expf(lvl - m);
      if (lane == 0) logu[ii] = -(__logf(e) + m);
    }
    grid.sync();
    // column pass: chunked (max, expsum) partials
    if (b < NT*8) {
      const int t = b >> 3, c = b & 7;
      const int o0 = offs[t], cnt = offs[t+1] - o0;
      const int s0 = o0 + (cnt*c)/8, s1 = o0 + (cnt*(c+1))/8;
      const int g = wv;
      float pm = -3.4e38f;
      for (int r = s0 + g; r < s1; r += 8) pm = fmaxf(pm, Ls[(size_t)r*KC + lane] + logu[r]);
      sm.sk.gred[g][lane] = pm;
      __syncthreads();
      if (g == 0) {
        float v = sm.sk.gred[0][lane];
        #pragma unroll
        for (int q = 1; q < 8; ++q) v = fmaxf(v, sm.sk.gred[q][lane]);
        sm.sk.gred[0][lane] = v;
      }
      __syncthreads();
      const float pmax = sm.sk.gred[0][lane];
      float ps = 0.f;
      for (int r = s0 + g; r < s1; r += 8) ps += __expf(Ls[(size_t)r*KC + lane] + logu[r] - pmax);
      __syncthreads();
      sm.sk.gred[g][lane] = ps;
      __syncthreads();
      if (wv == 0) {
        float v = 0.f;
        #pragma unroll
        for (int q = 0; q < 8; ++q) v += sm.sk.gred[q][lane];
        pmaxp[((t<<3)+c)*KC + lane] = pmax;
        psump[((t<<3)+c)*KC + lane] = v;
      }
    } else {
      const int c = b - NT*8;
      const int s0 = c*(NPT/8), s1 = s0 + NPT/8;
      float pm = -3.4e38f;
      for (int i = s0 + tid; i < s1; i += BT) pm = fmaxf(pm, logu[i]);
      for (int o = 32; o; o >>= 1) pm = fmaxf(pm, __shfl_xor(pm, o, 64));
      if (lane == 0) sm.sk.gred[0][wv] = pm;
      __syncthreads();
      if (tid == 0) {
        float m2 = -3.4e38f;
        #pragma unroll
        for (int w = 0; w < 8; ++w) m2 = fmaxf(m2, sm.sk.gred[0][w]);
        sm.sk.tmp[0] = m2;
      }
      __syncthreads();
      const float m2 = sm.sk.tmp[0];
      float ps = 0.f;
      for (int i = s0 + tid; i < s1; i += BT) ps += __expf(logu[i] - m2);
      for (int o = 32; o; o >>= 1) ps += __shfl_xor(ps, o, 64);
      __syncthreads();
      if (lane == 0) sm.sk.gred[0][wv] = ps;
      __syncthreads();
      if (tid == 0) {
        float a = 0.f;
        #pragma unroll
        for (int w = 0; w < 8; ++w) a += sm.sk.gred[0][w];
        lastp[c] = m2; lastp[8+c] = a;
      }
    }
    grid.sync();
  }

  // ===== phase V: active transport values -> logits region (orig row order) =====
  for (int s2 = tid; s2 <= NT*KC; s2 += BT) {
    if (s2 < NT*KC) {
      int t = s2 >> 6, j = s2 & 63;
      float m = -3.4e38f;
      #pragma unroll
      for (int c = 0; c < 8; ++c) m = fmaxf(m, pmaxp[((t<<3)+c)*KC + j]);
      float a = 0.f;
      #pragma unroll
      for (int c = 0; c < 8; ++c) a += psump[((t<<3)+c)*KC + j] * __expf(pmaxp[((t<<3)+c)*KC + j] - m);
      ((float*)sm.sk.lv)[s2] = -(__logf(a) + m);
    }
  }
  __syncthreads();
  for (int ii = wid; ii < NPT; ii += WAVES_MAIN) {
    int t = tsv[ii];
    int i = order[ii];
    float v = __expf(Ls[(size_t)ii*KC + lane] + logu[ii] + sm.sk.lv[t][lane]);
    vals[(size_t)i*KC + lane] = v;
  }
}

// ---------------- K6: expand vals into full T (zeros elsewhere) ----------------
__global__ __launch_bounds__(256) void k_T(const float* __restrict__ vals,
                                           const int* __restrict__ jt,
                                           float* __restrict__ T) {
  __shared__ float v[KC];
  const int i = blockIdx.x;
  const int tid = threadIdx.x;
  if (tid < KC) v[tid] = vals[(size_t)i*KC + tid];
  __syncthreads();
  const int t = jt[i];
  for (int e = tid; e < NSLOT; e += 256) {
    int j = e / NT;
    int tt = e - j*NT;
    T[(size_t)i*NSLOT + e] = (tt == t) ? v[j] : 0.0f;
  }
}

// ---------------- K7: logits = log(vals + 1e-8) in place ----------------
__global__ __launch_bounds__(256) void k_logits(float* logits) {
  int idx = blockIdx.x*256 + threadIdx.x;
  if (idx < NPT*KC) logits[idx] = logf(logits[idx] + 1e-8f);
}

extern "C" void kernel_launch(void* const* d_in, const int* in_sizes, int n_in,
                              void* d_out, int out_size, void* d_ws, size_t ws_size,
                              hipStream_t stream) {
  const float* emb    = (const float*)d_in[0];
  const float* pos    = (const float*)d_in[1];
  const float* W1     = (const float*)d_in[2];
  const float* b1     = (const float*)d_in[3];
  const float* protos = (const float*)d_in[4];
  const int*   jt     = (const int*)d_in[5];
  // d_in[6] = k (device scalar) — fixed at 64 by setup_inputs.

  float* out  = (float*)d_out;
  float* vals = out;                        // logits region (written last)
  float* T    = out + (size_t)NPT*KC;       // T region doubles as scratch
  float* TS   = T;

  unsigned* sub = (unsigned*)(TS + OFF_SUB);
  int* i0p = (int*)(TS + OFF_I0);

  hipLaunchKernelGGL(k_keys, dim3(1), dim3(64), 0, stream, sub, i0p);
  hipLaunchKernelGGL(k_gumbel, dim3((NPT + 255)/256, KC - 1), dim3(256), 0, stream,
                     sub, TS + OFF_Q);
  hipLaunchKernelGGL(k_gemm, dim3((NPT + 63)/64), dim3(256), 0, stream,
                     emb, W1, b1, TS + OFF_H);
  hipLaunchKernelGGL(k_cl, dim3((NPT + 3)/4), dim3(256), 0, stream,
                     TS + OFF_H, protos, TS + OFF_CL);

  const float* pos_a = pos; const int* jt_a = jt; float* TS_a = TS; float* vals_a = vals;
  void* kargs[] = { (void*)&pos_a, (void*)&jt_a, (void*)&TS_a, (void*)&vals_a };
  hipLaunchCooperativeKernel((const void*)k_main, dim3(G_MAIN), dim3(BT), kargs, 0, stream);

  hipLaunchKernelGGL(k_T, dim3(NPT), dim3(256), 0, stream, vals, jt, T);
  hipLaunchKernelGGL(k_logits, dim3((NPT*KC + 255)/256), dim3(256), 0, stream, vals);
}